// Round 1
// baseline (406.038 us; speedup 1.0000x reference)
//
#include <hip/hip_runtime.h>
#include <math.h>

#define BATCH    65536
#define FEAT     512
#define NCLASS   16
#define LAMDA    1.0f
#define LAMDA1   10.0f
#define SCALE    1.0f
#define EPS      1e-9f

constexpr int BLOCK  = 256;
constexpr int GRID   = 4096;
constexpr int NV     = BATCH * (FEAT / 4);     // 8,388,608 float4 elements
constexpr int STRIDE = GRID * BLOCK;           // 1,048,576
constexpr int ITERS  = NV / STRIDE;            // exactly 8

// Workspace layout (float slots):
//   [0, GRID)                : per-block partial sums
//   [GRID, GRID+256)         : gram[16][16] (row-major, j*16+k)
//   [GRID+256]               : arrival counter (uint), zeroed by memsetAsync
constexpr int WS_GRAM = GRID;
constexpr int WS_CTR  = GRID + NCLASS * NCLASS;

typedef float f4v __attribute__((ext_vector_type(4)));

// ---------------------------------------------------------------------------
// Fused kernel, GRID+1 blocks.
//   blocks [0,GRID)  : center-loss partials (identical math/order to before)
//   block  GRID      : 16x16 gram, identical per-thread 128-iter chain as the
//                      old finalize kernel -> bit-identical gram values, but
//                      computed CONCURRENTLY with (hidden under) the x stream
//                      instead of serially after it on one CU.
//   last-arriving block: reduces the 4096 partials (same order as old k2) and
//                      combines with gram -> bit-identical final result.
// Counter protocol: per-block release (__threadfence before atomicAdd);
// last block (old == GRID) acquires (__threadfence after observing count).
// atomicAdd on global is device-scope on CDNA -> safe across XCDs.
// ---------------------------------------------------------------------------
__global__ __launch_bounds__(BLOCK) void island_fused(
    const f4v* __restrict__ x,         // [BATCH * FEAT/4]
    const int* __restrict__ y,         // [BATCH]
    const f4v* __restrict__ centers4,  // [NCLASS * FEAT/4]
    float*     __restrict__ ws,        // see layout above
    float*     __restrict__ out)       // [1]
{
    __shared__ float wsum[4];
    __shared__ int   slast;

    float*        partials = ws;
    float*        gramws   = ws + WS_GRAM;
    unsigned int* ctr      = (unsigned int*)(ws + WS_CTR);

    const int bid  = blockIdx.x;
    const int lane = threadIdx.x & 63;
    const int wid  = threadIdx.x >> 6;

    if (bid < GRID) {
        // ---------------- center-loss streaming path (unchanged math) ------
        const int tid = bid * BLOCK + threadIdx.x;

        // wave-uniform sample-row base -> y loads become s_loads.
        const int base_b = __builtin_amdgcn_readfirstlane(tid >> 7);
        const int d4     = tid & 127;

        int cls[ITERS];
        #pragma unroll
        for (int it = 0; it < ITERS; ++it)
            cls[it] = y[base_b + it * (STRIDE >> 7)];

        // Issue all 8 nt loads up-front (8 outstanding dwordx4 per thread).
        f4v xv[ITERS];
        #pragma unroll
        for (int it = 0; it < ITERS; ++it)
            xv[it] = __builtin_nontemporal_load(&x[tid + it * STRIDE]);

        float sum = 0.0f;
        #pragma unroll
        for (int it = 0; it < ITERS; ++it) {
            f4v cv = centers4[cls[it] * (FEAT / 4) + d4];  // L1-hot (32 KB)
            f4v e  = xv[it] - cv;
            sum += e.x * e.x + e.y * e.y + e.z * e.z + e.w * e.w;
        }

        #pragma unroll
        for (int off = 32; off > 0; off >>= 1)
            sum += __shfl_down(sum, off, 64);

        if (lane == 0) wsum[wid] = sum;
        __syncthreads();
        if (threadIdx.x == 0)
            partials[bid] = wsum[0] + wsum[1] + wsum[2] + wsum[3];
    } else {
        // ---------------- gram block (exact old-finalize arithmetic) -------
        const int j = threadIdx.x >> 4;
        const int k = threadIdx.x & 15;
        const f4v* cj = centers4 + j * (FEAT / 4);
        const f4v* ck = centers4 + k * (FEAT / 4);
        float dot = 0.0f;
        #pragma unroll 8
        for (int i = 0; i < FEAT / 4; ++i) {
            f4v a = cj[i];
            f4v b = ck[i];
            dot += a.x * b.x + a.y * b.y + a.z * b.z + a.w * b.w;
        }
        gramws[threadIdx.x] = dot;
        __syncthreads();
    }

    // ---------------- arrival counter (release) ----------------------------
    if (threadIdx.x == 0) {
        __threadfence();                           // release my block's writes
        unsigned int old = atomicAdd(ctr, 1u);
        slast = (old == (unsigned int)GRID) ? 1 : 0;  // GRID+1 arrivals total
    }
    __syncthreads();

    // ---------------- last block finalizes (acquire) ------------------------
    if (slast) {
        __threadfence();                           // acquire all blocks' writes

        // Reduce 4096 partials — SAME order as the old finalize kernel.
        float psum = 0.0f;
        #pragma unroll
        for (int k2 = 0; k2 < GRID / 256; ++k2)
            psum += partials[threadIdx.x + k2 * 256];
        #pragma unroll
        for (int off = 32; off > 0; off >>= 1)
            psum += __shfl_down(psum, off, 64);

        if (lane == 0) wsum[wid] = psum;
        __syncthreads();

        if (threadIdx.x == 0) {
            float item1 = 0.0f;
            for (int jj = 0; jj < NCLASS; ++jj) {
                float nj = sqrtf(gramws[jj * NCLASS + jj]);
                for (int kk = jj + 1; kk < NCLASS; ++kk) {
                    float nk = sqrtf(gramws[kk * NCLASS + kk]);
                    item1 += gramws[jj * NCLASS + kk] / (nj * nk + EPS) + 1.0f;
                }
            }
            float total = wsum[0] + wsum[1] + wsum[2] + wsum[3];
            float loss_center = 0.5f * total * (SCALE / (float)BATCH);
            out[0] = LAMDA * (loss_center + LAMDA1 * item1);
        }
    }
}

extern "C" void kernel_launch(void* const* d_in, const int* in_sizes, int n_in,
                              void* d_out, int out_size, void* d_ws, size_t ws_size,
                              hipStream_t stream) {
    const float* x       = (const float*)d_in[0];   // [BATCH, FEAT]
    const int*   y       = (const int*)d_in[1];     // [BATCH]
    const float* centers = (const float*)d_in[2];   // [NCLASS, FEAT]
    float* out = (float*)d_out;
    float* ws  = (float*)d_ws;

    // ws is re-poisoned every iteration -> zero the arrival counter only.
    hipMemsetAsync((char*)d_ws + (size_t)WS_CTR * sizeof(float), 0,
                   sizeof(unsigned int), stream);

    island_fused<<<GRID + 1, BLOCK, 0, stream>>>(
        (const f4v*)x, y, (const f4v*)centers, ws, out);
}

// Round 2
// 250.475 us; speedup vs baseline: 1.6211x; 1.6211x over previous
//
#include <hip/hip_runtime.h>
#include <math.h>

#define BATCH    65536
#define FEAT     512
#define NCLASS   16
#define LAMDA    1.0f
#define LAMDA1   10.0f
#define SCALE    1.0f
#define EPS      1e-9f

constexpr int BLOCK  = 256;
constexpr int GRID   = 4096;
constexpr int NV     = BATCH * (FEAT / 4);     // 8,388,608 float4 elements
constexpr int STRIDE = GRID * BLOCK;           // 1,048,576
constexpr int ITERS  = NV / STRIDE;            // exactly 8

// Workspace layout (float slots):
//   [0, GRID)          : per-block partial sums
//   [GRID, GRID+256)   : gram[16][16] (row-major, j*16+k)
//   [GRID+256]         : arrival counter (uint), zeroed by memsetAsync
constexpr int WS_GRAM = GRID;
constexpr int WS_CTR  = GRID + NCLASS * NCLASS;

typedef float f4v __attribute__((ext_vector_type(4)));

// ---------------------------------------------------------------------------
// R1 lesson: __threadfence() per block = buffer_wbl2+buffer_inv (full L2
// writeback+invalidate, XCDs non-coherent) x 4097 blocks -> 255 us of idle
// serialization. Fix: NO fences. All cross-block traffic goes through
// agent-scope RELAXED atomics, which compile to write-through sc0/sc1
// accesses serviced at the MALL coherence point — no cache maintenance.
// Producer-side ordering (data store -> counter bump) is a plain
// s_waitcnt vmcnt(0): the sc1 store has reached the coherence point when
// vmcnt retires, and the atomic executes at that same point.
// Consumer-side: agent-relaxed loads bypass the consumer's (possibly
// stale) L1/L2 by construction; they are issued only after the atomic's
// result is known (data dependence), so no acquire fence is needed.
// ---------------------------------------------------------------------------
__device__ __forceinline__ void st_agent(float* p, float v) {
    __hip_atomic_store(p, v, __ATOMIC_RELAXED, __HIP_MEMORY_SCOPE_AGENT);
}
__device__ __forceinline__ float ld_agent(const float* p) {
    return __hip_atomic_load(p, __ATOMIC_RELAXED, __HIP_MEMORY_SCOPE_AGENT);
}

__global__ __launch_bounds__(BLOCK) void island_fused(
    const f4v* __restrict__ x,         // [BATCH * FEAT/4]
    const int* __restrict__ y,         // [BATCH]
    const f4v* __restrict__ centers4,  // [NCLASS * FEAT/4]
    float*     __restrict__ ws,        // see layout above
    float*     __restrict__ out)       // [1]
{
    __shared__ float wsum[4];
    __shared__ int   slast;

    float*        partials = ws;
    float*        gramws   = ws + WS_GRAM;
    unsigned int* ctr      = (unsigned int*)(ws + WS_CTR);

    const int bid  = blockIdx.x;
    const int lane = threadIdx.x & 63;
    const int wid  = threadIdx.x >> 6;

    if (bid < GRID) {
        // ---------------- center-loss streaming path (round-0 exact form) --
        const int tid = bid * BLOCK + threadIdx.x;

        // wave-uniform sample-row base -> y loads become s_loads.
        const int base_b = __builtin_amdgcn_readfirstlane(tid >> 7);
        const int d4     = tid & 127;

        int cls[ITERS];
        #pragma unroll
        for (int it = 0; it < ITERS; ++it)
            cls[it] = y[base_b + it * (STRIDE >> 7)];

        float sum = 0.0f;
        #pragma unroll
        for (int it = 0; it < ITERS; ++it) {
            // nt: no L1/L2 allocation; x is MALL-resident (134 MB < 256 MB),
            // centers table stays L1/L2-hot.
            f4v xv = __builtin_nontemporal_load(&x[tid + it * STRIDE]);
            f4v cv = centers4[cls[it] * (FEAT / 4) + d4];
            f4v e  = xv - cv;
            sum += e.x * e.x + e.y * e.y + e.z * e.z + e.w * e.w;
        }

        #pragma unroll
        for (int off = 32; off > 0; off >>= 1)
            sum += __shfl_down(sum, off, 64);

        if (lane == 0) wsum[wid] = sum;
        __syncthreads();
        if (threadIdx.x == 0)
            st_agent(&partials[bid], wsum[0] + wsum[1] + wsum[2] + wsum[3]);
    } else {
        // ---------------- gram block (exact old-finalize arithmetic) -------
        // Runs CONCURRENTLY with the streaming blocks (hidden under them).
        const int j = threadIdx.x >> 4;
        const int k = threadIdx.x & 15;
        const f4v* cj = centers4 + j * (FEAT / 4);
        const f4v* ck = centers4 + k * (FEAT / 4);
        float dot = 0.0f;
        #pragma unroll 8
        for (int i = 0; i < FEAT / 4; ++i) {
            f4v a = cj[i];
            f4v b = ck[i];
            dot += a.x * b.x + a.y * b.y + a.z * b.z + a.w * b.w;
        }
        st_agent(&gramws[threadIdx.x], dot);
        // Each thread drains ITS OWN sc1 store before the barrier, so
        // thread 0's subsequent counter bump publishes all 256 of them.
        asm volatile("s_waitcnt vmcnt(0)" ::: "memory");
        __syncthreads();
    }

    // ---------------- arrival counter (no fence) ----------------------------
    if (threadIdx.x == 0) {
        asm volatile("s_waitcnt vmcnt(0)" ::: "memory");  // my sc1 store is at MALL
        unsigned int old = __hip_atomic_fetch_add(
            ctr, 1u, __ATOMIC_RELAXED, __HIP_MEMORY_SCOPE_AGENT);
        slast = (old == (unsigned int)GRID) ? 1 : 0;      // GRID+1 arrivals
    }
    __syncthreads();

    // ---------------- last block finalizes ----------------------------------
    if (slast) {
        // Reduce 4096 partials — SAME order as the old finalize kernel.
        float psum = 0.0f;
        #pragma unroll
        for (int k2 = 0; k2 < GRID / 256; ++k2)
            psum += ld_agent(&partials[threadIdx.x + k2 * 256]);
        #pragma unroll
        for (int off = 32; off > 0; off >>= 1)
            psum += __shfl_down(psum, off, 64);

        if (lane == 0) wsum[wid] = psum;
        __syncthreads();

        if (threadIdx.x == 0) {
            float item1 = 0.0f;
            for (int jj = 0; jj < NCLASS; ++jj) {
                float nj = sqrtf(ld_agent(&gramws[jj * NCLASS + jj]));
                for (int kk = jj + 1; kk < NCLASS; ++kk) {
                    float nk = sqrtf(ld_agent(&gramws[kk * NCLASS + kk]));
                    item1 += ld_agent(&gramws[jj * NCLASS + kk]) / (nj * nk + EPS) + 1.0f;
                }
            }
            float total = wsum[0] + wsum[1] + wsum[2] + wsum[3];
            float loss_center = 0.5f * total * (SCALE / (float)BATCH);
            out[0] = LAMDA * (loss_center + LAMDA1 * item1);
        }
    }
}

extern "C" void kernel_launch(void* const* d_in, const int* in_sizes, int n_in,
                              void* d_out, int out_size, void* d_ws, size_t ws_size,
                              hipStream_t stream) {
    const float* x       = (const float*)d_in[0];   // [BATCH, FEAT]
    const int*   y       = (const int*)d_in[1];     // [BATCH]
    const float* centers = (const float*)d_in[2];   // [NCLASS, FEAT]
    float* out = (float*)d_out;
    float* ws  = (float*)d_ws;

    // ws is re-poisoned every iteration -> zero the arrival counter only.
    hipMemsetAsync((char*)d_ws + (size_t)WS_CTR * sizeof(float), 0,
                   sizeof(unsigned int), stream);

    island_fused<<<GRID + 1, BLOCK, 0, stream>>>(
        (const f4v*)x, y, (const f4v*)centers, ws, out);
}

// Round 3
// 203.006 us; speedup vs baseline: 2.0001x; 1.2338x over previous
//
#include <hip/hip_runtime.h>
#include <math.h>

#define BATCH    65536
#define FEAT     512
#define NCLASS   16
#define LAMDA    1.0f
#define LAMDA1   10.0f
#define SCALE    1.0f
#define EPS      1e-9f

constexpr int BLOCK  = 256;
constexpr int GRID   = 4096;
constexpr int NV     = BATCH * (FEAT / 4);     // 8,388,608 float4 elements
constexpr int STRIDE = GRID * BLOCK;           // 1,048,576
constexpr int ITERS  = NV / STRIDE;            // exactly 8

// Workspace layout (float slots):
//   [0, GRID)  : per-block partial sums
//   [GRID]     : item1 (gram cosine sum), computed by block GRID of k1
constexpr int WS_ITEM1 = GRID;

typedef float f4v __attribute__((ext_vector_type(4)));

// ---------------------------------------------------------------------------
// R2 lesson: single-kernel termination (4097 same-line agent atomics + per-
// block vmcnt(0) tails) cost ~40 us vs the two-kernel structure (k1+k2 = 53us
// in R0). Revert to two kernels: the stream-ordered kernel boundary is the
// cheapest "barrier + fence" available (end-of-kernel release, no atomics).
//
// Kernel 1, GRID+1 blocks:
//   blocks [0,GRID): center-loss partials. All 8 nt loads are issued UP-FRONT
//     (independent, 8 KB in flight per wave) so MALL/HBM latency (~600-900cy)
//     is covered by MLP, not just occupancy. Arithmetic order unchanged.
//   block GRID: 16x16 gram + the serial 120-pair item1 loop — identical
//     arithmetic/order to the old finalize, but hidden UNDER the x stream
//     instead of serialized after it. Plain stores; end-of-kernel release
//     publishes them to kernel 2.
// ---------------------------------------------------------------------------
__global__ __launch_bounds__(BLOCK) void island_main(
    const f4v* __restrict__ x,         // [BATCH * FEAT/4]
    const int* __restrict__ y,         // [BATCH]
    const f4v* __restrict__ centers4,  // [NCLASS * FEAT/4]
    float*     __restrict__ ws)        // see layout above
{
    __shared__ float wsum[4];
    __shared__ float gram[NCLASS][NCLASS];

    const int bid  = blockIdx.x;
    const int lane = threadIdx.x & 63;
    const int wid  = threadIdx.x >> 6;

    if (bid < GRID) {
        // ---------------- center-loss streaming path ----------------------
        const int tid = bid * BLOCK + threadIdx.x;

        // wave-uniform sample-row base -> y loads become s_loads.
        const int base_b = __builtin_amdgcn_readfirstlane(tid >> 7);
        const int d4     = tid & 127;

        int cls[ITERS];
        #pragma unroll
        for (int it = 0; it < ITERS; ++it)
            cls[it] = y[base_b + it * (STRIDE >> 7)];

        // Issue all 8 independent nt loads BEFORE any consumption: 8 x 1KB
        // per wave in flight -> covers ~900cy HBM latency via MLP.
        f4v xv[ITERS];
        #pragma unroll
        for (int it = 0; it < ITERS; ++it)
            xv[it] = __builtin_nontemporal_load(&x[tid + it * STRIDE]);

        float sum = 0.0f;
        #pragma unroll
        for (int it = 0; it < ITERS; ++it) {
            f4v cv = centers4[cls[it] * (FEAT / 4) + d4];  // L1/L2-hot, 32KB
            f4v e  = xv[it] - cv;
            sum += e.x * e.x + e.y * e.y + e.z * e.z + e.w * e.w;
        }

        #pragma unroll
        for (int off = 32; off > 0; off >>= 1)
            sum += __shfl_down(sum, off, 64);

        if (lane == 0) wsum[wid] = sum;
        __syncthreads();
        if (threadIdx.x == 0)
            ws[bid] = wsum[0] + wsum[1] + wsum[2] + wsum[3];
    } else {
        // ---------------- gram + item1 (hidden under the stream) ----------
        const int j = threadIdx.x >> 4;
        const int k = threadIdx.x & 15;
        const f4v* cj = centers4 + j * (FEAT / 4);
        const f4v* ck = centers4 + k * (FEAT / 4);
        float dot = 0.0f;
        #pragma unroll 8
        for (int i = 0; i < FEAT / 4; ++i) {
            f4v a = cj[i];
            f4v b = ck[i];
            dot += a.x * b.x + a.y * b.y + a.z * b.z + a.w * b.w;
        }
        gram[j][k] = dot;
        __syncthreads();

        if (threadIdx.x == 0) {
            // EXACT old-finalize item1 arithmetic/order.
            float item1 = 0.0f;
            for (int jj = 0; jj < NCLASS; ++jj) {
                float nj = sqrtf(gram[jj][jj]);
                for (int kk = jj + 1; kk < NCLASS; ++kk) {
                    float nk = sqrtf(gram[kk][kk]);
                    item1 += gram[jj][kk] / (nj * nk + EPS) + 1.0f;
                }
            }
            ws[WS_ITEM1] = item1;
        }
    }
}

// ---------------------------------------------------------------------------
// Kernel 2 (single block): bare 4096-partial reduce + combine. ~2-3 us.
// Same reduction order as all previous rounds -> bit-identical result.
// ---------------------------------------------------------------------------
__global__ __launch_bounds__(256) void finalize_kernel(
    const float* __restrict__ ws,   // partials [GRID] + item1 at [WS_ITEM1]
    float*       __restrict__ out)  // [1]
{
    float psum = 0.0f;
    #pragma unroll
    for (int k = 0; k < GRID / 256; ++k)
        psum += ws[threadIdx.x + k * 256];
    #pragma unroll
    for (int off = 32; off > 0; off >>= 1)
        psum += __shfl_down(psum, off, 64);

    __shared__ float wsum[4];
    const int lane = threadIdx.x & 63;
    const int wid  = threadIdx.x >> 6;
    if (lane == 0) wsum[wid] = psum;
    __syncthreads();

    if (threadIdx.x == 0) {
        float total = wsum[0] + wsum[1] + wsum[2] + wsum[3];
        float loss_center = 0.5f * total * (SCALE / (float)BATCH);
        out[0] = LAMDA * (loss_center + LAMDA1 * ws[WS_ITEM1]);
    }
}

extern "C" void kernel_launch(void* const* d_in, const int* in_sizes, int n_in,
                              void* d_out, int out_size, void* d_ws, size_t ws_size,
                              hipStream_t stream) {
    const float* x       = (const float*)d_in[0];   // [BATCH, FEAT]
    const int*   y       = (const int*)d_in[1];     // [BATCH]
    const float* centers = (const float*)d_in[2];   // [NCLASS, FEAT]
    float* out = (float*)d_out;
    float* ws  = (float*)d_ws;

    island_main<<<GRID + 1, BLOCK, 0, stream>>>(
        (const f4v*)x, y, (const f4v*)centers, ws);

    finalize_kernel<<<1, 256, 0, stream>>>(ws, out);
}